// Round 1
// baseline (517.935 us; speedup 1.0000x reference)
//
#include <hip/hip_runtime.h>

// FBCritic: C[i][j] = dot(W_f[fwd_idx[i]], W_b[bwd_idx[j]]), B=8192, D=64.
// Write-bound: 256 MB fp32 output. bf16 MFMA (16x16x32) keeps compute off the
// critical path (fp32 VALU would cost 55us > 41us write floor).

#define NUM_OBS 100000
#define NUM_ACT 10
#define DREPR   64

typedef __bf16 bf16x8 __attribute__((ext_vector_type(8)));
typedef float  f32x4  __attribute__((ext_vector_type(4)));

__device__ __forceinline__ bf16x8 cvt8(float4 a, float4 b) {
    bf16x8 r;
    r[0] = (__bf16)a.x; r[1] = (__bf16)a.y; r[2] = (__bf16)a.z; r[3] = (__bf16)a.w;
    r[4] = (__bf16)b.x; r[5] = (__bf16)b.y; r[6] = (__bf16)b.z; r[7] = (__bf16)b.w;
    return r;
}

__device__ __forceinline__ int ravel_clip(int o, int a) {
    o = o < 0 ? 0 : (o > NUM_OBS - 1 ? NUM_OBS - 1 : o);
    a = a < 0 ? 0 : (a > NUM_ACT - 1 ? NUM_ACT - 1 : a);
    return o * NUM_ACT + a;
}

// Load the two K-step MFMA A/B fragments for one 16-row block directly from
// the embedding table. Fragment layout for mfma_f32_16x16x32_bf16 operands:
// lane holds [row = lane&15][k = (lane>>4)*8 + j], j in 0..7 -> 32 contiguous
// bytes of fp32 per lane per K-step, converted to bf16 in-register.
__device__ __forceinline__ void load_frags(const int* __restrict__ obs,
                                           const int* __restrict__ act,
                                           const float* __restrict__ W,
                                           int row, int q,
                                           bf16x8& f0, bf16x8& f1) {
    int idx = ravel_clip(obs[row], act[row]);
    const float* base = W + (long)idx * DREPR + q * 8;
    const float4* p0 = reinterpret_cast<const float4*>(base);        // k in [q*8, q*8+8)
    const float4* p1 = reinterpret_cast<const float4*>(base + 32);   // k in [32+q*8, ...)
    float4 a0 = p0[0], a1 = p0[1];
    float4 b0 = p1[0], b1 = p1[1];
    f0 = cvt8(a0, a1);
    f1 = cvt8(b0, b1);
}

__global__ __launch_bounds__(256, 2) void fbcritic_kernel(
    const int* __restrict__ obs, const int* __restrict__ act,
    const int* __restrict__ fobs, const int* __restrict__ fact,
    const float* __restrict__ Wf, const float* __restrict__ Wb,
    float* __restrict__ out, int ldc) {
    const int tid  = threadIdx.x;
    const int lane = tid & 63;
    const int wave = tid >> 6;
    const int l16  = lane & 15;
    const int q    = lane >> 4;

    // 128x128 block tile; 4 waves in 2x2, each wave owns 64x64.
    const int m_base = blockIdx.y * 128 + (wave >> 1) * 64;
    const int n_base = blockIdx.x * 128 + (wave & 1) * 64;

    bf16x8 afrag[4][2];  // [m-block][k-step]
    bf16x8 bfrag[4][2];  // [n-block][k-step]

#pragma unroll
    for (int mb = 0; mb < 4; ++mb)
        load_frags(obs, act, Wf, m_base + mb * 16 + l16, q,
                   afrag[mb][0], afrag[mb][1]);
#pragma unroll
    for (int nb = 0; nb < 4; ++nb)
        load_frags(fobs, fact, Wb, n_base + nb * 16 + l16, q,
                   bfrag[nb][0], bfrag[nb][1]);

    f32x4 acc[4][4];
#pragma unroll
    for (int mb = 0; mb < 4; ++mb)
#pragma unroll
        for (int nb = 0; nb < 4; ++nb)
            acc[mb][nb] = f32x4{0.f, 0.f, 0.f, 0.f};

#pragma unroll
    for (int ks = 0; ks < 2; ++ks)
#pragma unroll
        for (int mb = 0; mb < 4; ++mb)
#pragma unroll
            for (int nb = 0; nb < 4; ++nb)
                acc[mb][nb] = __builtin_amdgcn_mfma_f32_16x16x32_bf16(
                    afrag[mb][ks], bfrag[nb][ks], acc[mb][nb], 0, 0, 0);

    // C/D layout: col = lane&15, row = (lane>>4)*4 + reg  [measured m89/m91]
#pragma unroll
    for (int mb = 0; mb < 4; ++mb) {
        const int r0 = m_base + mb * 16 + q * 4;
#pragma unroll
        for (int nb = 0; nb < 4; ++nb) {
            const int c = n_base + nb * 16 + l16;
            float* o = out + (size_t)r0 * ldc + c;
#pragma unroll
            for (int r = 0; r < 4; ++r)
                o[(size_t)r * ldc] = acc[mb][nb][r];
        }
    }
}

extern "C" void kernel_launch(void* const* d_in, const int* in_sizes, int n_in,
                              void* d_out, int out_size, void* d_ws, size_t ws_size,
                              hipStream_t stream) {
    const int*   obs  = (const int*)d_in[0];
    const int*   act  = (const int*)d_in[1];
    const int*   fobs = (const int*)d_in[2];
    const int*   fact = (const int*)d_in[3];
    const float* Wf   = (const float*)d_in[4];
    const float* Wb   = (const float*)d_in[5];
    float* out = (float*)d_out;

    const int B = in_sizes[0];  // 8192
    dim3 grid(B / 128, B / 128);
    fbcritic_kernel<<<grid, 256, 0, stream>>>(obs, act, fobs, fact, Wf, Wb, out, B);
}

// Round 2
// 485.501 us; speedup vs baseline: 1.0668x; 1.0668x over previous
//
#include <hip/hip_runtime.h>

// FBCritic: C[i][j] = dot(W_f[fwd_idx[i]], W_b[bwd_idx[j]]), B=8192, D=64.
// Roofline: 256 MB fp32 output write @ ~6.3 TB/s => ~41 us floor.
// Two-phase: (1) gather rows once -> compact bf16 tables in d_ws (2 MB, L2-resident)
//            (2) dense bf16 MFMA GEMM, LDS-transposed epilogue for coalesced stores.

#define NUM_OBS 100000
#define NUM_ACT 10
#define DREPR   64
#define BROWS   8192

typedef __bf16 bf16x8 __attribute__((ext_vector_type(8)));
typedef float  f32x4  __attribute__((ext_vector_type(4)));

__device__ __forceinline__ int ravel_clip(int o, int a) {
    o = o < 0 ? 0 : (o > NUM_OBS - 1 ? NUM_OBS - 1 : o);
    a = a < 0 ? 0 : (a > NUM_ACT - 1 ? NUM_ACT - 1 : a);
    return o * NUM_ACT + a;
}

// Phase 1: gather W[ravel(obs,act)] rows into compact bf16 table dst[r][64].
// 8 threads per row (8 floats each): reads full 64-B lines of the fp32 table,
// writes fully coalesced 16-B bf16 segments. One gather per row total.
__global__ __launch_bounds__(256) void gather_convert_kernel(
    const int* __restrict__ obs, const int* __restrict__ act,
    const float* __restrict__ W, __bf16* __restrict__ dst, int rows_per_block) {
    const int t = threadIdx.x;
    const int r = blockIdx.x * rows_per_block + (t >> 3);   // row in [0, BROWS)
    const int seg = t & 7;                                   // 8 floats per thread
    const int idx = ravel_clip(obs[r], act[r]);
    const float* src = W + (long)idx * DREPR + seg * 8;
    float4 a = reinterpret_cast<const float4*>(src)[0];
    float4 b = reinterpret_cast<const float4*>(src)[1];
    bf16x8 v;
    v[0] = (__bf16)a.x; v[1] = (__bf16)a.y; v[2] = (__bf16)a.z; v[3] = (__bf16)a.w;
    v[4] = (__bf16)b.x; v[5] = (__bf16)b.y; v[6] = (__bf16)b.z; v[7] = (__bf16)b.w;
    *reinterpret_cast<bf16x8*>(dst + (long)r * DREPR + seg * 8) = v;
}

// Phase 2: C = Af @ Bf^T from compact bf16 tables. 128x128 tile per block,
// 4 waves in 2x2, each wave 64x64 via 16 x mfma_f32_16x16x32_bf16 x 2 K-steps.
__global__ __launch_bounds__(256, 2) void fbcritic_gemm_kernel(
    const __bf16* __restrict__ Af, const __bf16* __restrict__ Bf,
    float* __restrict__ out, int ldc) {
    const int tid  = threadIdx.x;
    const int lane = tid & 63;
    const int wave = tid >> 6;
    const int l16  = lane & 15;
    const int q    = lane >> 4;

    const int m_tile = blockIdx.y * 128;
    const int n_tile = blockIdx.x * 128;
    const int m_base = m_tile + (wave >> 1) * 64;
    const int n_base = n_tile + (wave & 1) * 64;

    // A-operand layout: lane holds [row = lane&15][k = (lane>>4)*8 + j].
    // Compact row is 64 bf16 = 128 B; fragment = 16 B at row*128 + ks*64 + q*16.
    bf16x8 afrag[4][2], bfrag[4][2];
#pragma unroll
    for (int mb = 0; mb < 4; ++mb) {
        const __bf16* p = Af + (long)(m_base + mb * 16 + l16) * DREPR + q * 8;
        afrag[mb][0] = *reinterpret_cast<const bf16x8*>(p);
        afrag[mb][1] = *reinterpret_cast<const bf16x8*>(p + 32);
    }
#pragma unroll
    for (int nb = 0; nb < 4; ++nb) {
        const __bf16* p = Bf + (long)(n_base + nb * 16 + l16) * DREPR + q * 8;
        bfrag[nb][0] = *reinterpret_cast<const bf16x8*>(p);
        bfrag[nb][1] = *reinterpret_cast<const bf16x8*>(p + 32);
    }

    f32x4 acc[4][4];
#pragma unroll
    for (int mb = 0; mb < 4; ++mb)
#pragma unroll
        for (int nb = 0; nb < 4; ++nb)
            acc[mb][nb] = f32x4{0.f, 0.f, 0.f, 0.f};

#pragma unroll
    for (int ks = 0; ks < 2; ++ks)
#pragma unroll
        for (int mb = 0; mb < 4; ++mb)
#pragma unroll
            for (int nb = 0; nb < 4; ++nb)
                acc[mb][nb] = __builtin_amdgcn_mfma_f32_16x16x32_bf16(
                    afrag[mb][ks], bfrag[nb][ks], acc[mb][nb], 0, 0, 0);

    // Epilogue: C/D layout (col=lane&15, row=q*4+reg) -> LDS (stride 132:
    // write pattern is 2-way bank aliased = free) -> coalesced float4 stores.
    __shared__ float lds[128 * 132];
    const int wr0 = (wave >> 1) * 64 + q * 4;   // local row base for this lane
    const int wc0 = (wave & 1) * 64 + l16;      // local col for this lane
#pragma unroll
    for (int mb = 0; mb < 4; ++mb)
#pragma unroll
        for (int nb = 0; nb < 4; ++nb) {
            float* p = &lds[(wr0 + mb * 16) * 132 + wc0 + nb * 16];
#pragma unroll
            for (int r = 0; r < 4; ++r)
                p[r * 132] = acc[mb][nb][r];
        }
    __syncthreads();

    // 128 rows x 128 floats = 4096 float4; 256 threads x 16 iters, coalesced.
#pragma unroll
    for (int i = 0; i < 16; ++i) {
        const int t = tid + i * 256;
        const int row = t >> 5;
        const int col = (t & 31) * 4;
        f32x4 v = *reinterpret_cast<const f32x4*>(&lds[row * 132 + col]);
        *reinterpret_cast<f32x4*>(out + (size_t)(m_tile + row) * ldc + n_tile + col) = v;
    }
}

extern "C" void kernel_launch(void* const* d_in, const int* in_sizes, int n_in,
                              void* d_out, int out_size, void* d_ws, size_t ws_size,
                              hipStream_t stream) {
    const int*   obs  = (const int*)d_in[0];
    const int*   act  = (const int*)d_in[1];
    const int*   fobs = (const int*)d_in[2];
    const int*   fact = (const int*)d_in[3];
    const float* Wf   = (const float*)d_in[4];
    const float* Wb   = (const float*)d_in[5];
    float* out = (float*)d_out;

    const int B = in_sizes[0];  // 8192
    __bf16* Af = (__bf16*)d_ws;
    __bf16* Bf = Af + (size_t)B * DREPR;

    // Phase 1: 256 threads = 32 rows/block.
    const int rows_per_block = 256 / 8;
    gather_convert_kernel<<<B / rows_per_block, 256, 0, stream>>>(obs, act, Wf, Af, rows_per_block);
    gather_convert_kernel<<<B / rows_per_block, 256, 0, stream>>>(fobs, fact, Wb, Bf, rows_per_block);

    // Phase 2: 128x128 tiles.
    dim3 grid(B / 128, B / 128);
    fbcritic_gemm_kernel<<<grid, 256, 0, stream>>>(Af, Bf, out, B);
}